// Round 5
// baseline (85.128 us; speedup 1.0000x reference)
//
#include <hip/hip_runtime.h>

#define IN_F 4096
#define OUT_F 4096
#define MTOK 1024   // 2*512 tokens
#define RANK 16
#define GROUP 128

typedef short bf16x8 __attribute__((ext_vector_type(8)));
typedef float f32x4 __attribute__((ext_vector_type(4)));

__device__ __forceinline__ unsigned short f2bf(float f) {
  unsigned int u = __float_as_uint(f);
  u += 0x7fff + ((u >> 16) & 1);   // round-to-nearest-even
  return (unsigned short)(u >> 16);
}

// ---------------- kernel 1: W_q = fake_quant(w0 + lora_b @ lora_a) -> bf16 ----------------
#define QROWS 8
__global__ __launch_bounds__(256) void quant_w(const float* __restrict__ w0,
                                               const float* __restrict__ la,
                                               const float* __restrict__ lb,
                                               const float* __restrict__ qs,
                                               unsigned short* __restrict__ wq) {
  const int bid = blockIdx.x;        // 2048 blocks: (4096/QROWS) rowgroups x 4 colblocks
  const int cb  = bid & 3;
  const int rg  = bid >> 2;
  const int i   = cb * 1024 + (threadIdx.x << 2);
  const int o0  = rg * QROWS;

  float4 areg[RANK];
  #pragma unroll
  for (int r = 0; r < RANK; ++r)
    areg[r] = *reinterpret_cast<const float4*>(&la[r * IN_F + i]);

  #pragma unroll
  for (int ro = 0; ro < QROWS; ++ro) {
    const int o = o0 + ro;
    float4 w = *reinterpret_cast<const float4*>(&w0[(size_t)o * IN_F + i]);
    const float* lbr = &lb[o * RANK];
    #pragma unroll
    for (int r = 0; r < RANK; ++r) {
      const float b = lbr[r];
      w.x = fmaf(b, areg[r].x, w.x);
      w.y = fmaf(b, areg[r].y, w.y);
      w.z = fmaf(b, areg[r].z, w.z);
      w.w = fmaf(b, areg[r].w, w.w);
    }
    const float s  = qs[o * (IN_F / GROUP) + (i >> 7)];
    const float se = s + 1e-9f;
    ushort4 ov;
    ov.x = f2bf(rintf(fminf(fmaxf(w.x / se, -8.f), 7.f)) * s);
    ov.y = f2bf(rintf(fminf(fmaxf(w.y / se, -8.f), 7.f)) * s);
    ov.z = f2bf(rintf(fminf(fmaxf(w.z / se, -8.f), 7.f)) * s);
    ov.w = f2bf(rintf(fminf(fmaxf(w.w / se, -8.f), 7.f)) * s);
    *reinterpret_cast<ushort4*>(&wq[(size_t)o * IN_F + i]) = ov;
  }
}

// ---------------- kernel 2: x f32 -> bf16 ----------------
__global__ __launch_bounds__(256) void cvt_x(const float* __restrict__ x,
                                             unsigned short* __restrict__ xb) {
  const int i = (blockIdx.x * 256 + threadIdx.x) << 2;
  float4 v = *reinterpret_cast<const float4*>(&x[i]);
  ushort4 ov;
  ov.x = f2bf(v.x); ov.y = f2bf(v.y); ov.z = f2bf(v.z); ov.w = f2bf(v.w);
  *reinterpret_cast<ushort4*>(&xb[i]) = ov;
}

// ---------------- kernel 3: C[M,N] = A[M,K]*B[N,K]^T + bias, bf16 MFMA ----------------
// 256 threads = 2 K-groups x 2 waves. Block tile 64x128; each group does K=2048.
// Wave tile 64x64 (4x4 frags of 16x16x32): 16 MFMA per 8 ds_read_b128.
// LDS: per group 2 buf x (A[64][32] + B[128][32]) shorts = 24KB; total 48KB -> 2 blocks/CU.
// Chunk swizzle (4 chunks/row): phys = log ^ (row&3) ^ ((row>>2)&3); applied on global
// source, LDS stays linear (global_load_lds writes base+lane*16).
#define BM 64
#define BN 128
#define BK 32
#define KSPLIT 2
#define KHALF (IN_F / KSPLIT)   // 2048
#define NT (KHALF / BK)         // 64
#define GROWS (BM + BN)         // 192 rows per buffer
#define GBUFS (GROWS * BK)      // 6144 shorts = 12KB

__device__ __forceinline__ void load_lds16(const void* gsrc, void* ldst) {
  __builtin_amdgcn_global_load_lds(
      (const __attribute__((address_space(1))) unsigned int*)gsrc,
      (__attribute__((address_space(3))) unsigned int*)ldst, 16, 0, 0);
}

__global__ __launch_bounds__(256, 2) void gemm_bt(const unsigned short* __restrict__ A,
                                                  const unsigned short* __restrict__ B,
                                                  const float* __restrict__ bias,
                                                  float* __restrict__ C) {
  __shared__ unsigned short lds[2 * 2 * GBUFS];   // [grp][buf][6144] = 48KB
  const int tid  = threadIdx.x;
  const int lane = tid & 63;
  const int wave = tid >> 6;
  const int grp  = wave >> 1;                     // K-group (0: k<2048, 1: k>=2048)
  const int w    = wave & 1;                      // N-half within 128 cols
  const int r16  = lane & 15;
  const int hi   = lane >> 4;
  const int mBase = blockIdx.y * BM;
  const int nBase = blockIdx.x * BN;

  unsigned short* gl = &lds[grp * 2 * GBUFS];
  const int kOff = grp * KHALF;

  auto stage = [&](int buf, int kt) {
    const int kcol = kOff + kt * BK;
    #pragma unroll
    for (int j = 0; j < 6; ++j) {
      const int chunk = (tid & 127) + j * 128;    // 768 chunks of 16B per group buffer
      const int row   = chunk >> 2;               // 4 chunks per 32-short row
      const int clog  = (chunk & 3) ^ (row & 3) ^ ((row >> 2) & 3);
      const unsigned short* src = (row < BM)
          ? (A + (size_t)(mBase + row) * IN_F + kcol + clog * 8)
          : (B + (size_t)(nBase + row - BM) * IN_F + kcol + clog * 8);
      load_lds16(src, &gl[buf * GBUFS + (chunk - lane) * 8]);
    }
  };

  f32x4 acc[4][4];
  #pragma unroll
  for (int m = 0; m < 4; ++m)
    #pragma unroll
    for (int n = 0; n < 4; ++n)
      acc[m][n] = (f32x4){0.f, 0.f, 0.f, 0.f};

  stage(0, 0);
  int cur = 0;
  for (int kt = 0; kt < NT; ++kt) {
    __syncthreads();                       // stage(cur) drained; cur^1 free
    if (kt + 1 < NT) stage(cur ^ 1, kt + 1);
    const unsigned short* Ls = &gl[cur * GBUFS];
    bf16x8 af[4], bq[4];
    #pragma unroll
    for (int m = 0; m < 4; ++m) {
      const int row = m * 16 + r16;
      const int c = hi ^ (row & 3) ^ ((row >> 2) & 3);
      af[m] = *reinterpret_cast<const bf16x8*>(&Ls[row * BK + c * 8]);
    }
    #pragma unroll
    for (int n = 0; n < 4; ++n) {
      const int row = BM + w * 64 + n * 16 + r16;
      const int c = hi ^ (row & 3) ^ ((row >> 2) & 3);
      bq[n] = *reinterpret_cast<const bf16x8*>(&Ls[row * BK + c * 8]);
    }
    #pragma unroll
    for (int m = 0; m < 4; ++m)
      #pragma unroll
      for (int n = 0; n < 4; ++n)
        acc[m][n] = __builtin_amdgcn_mfma_f32_16x16x32_bf16(af[m], bq[n], acc[m][n], 0, 0, 0);
    cur ^= 1;
  }

  // ---- cross-group reduce through LDS (reuse staging space; all reads done) ----
  __syncthreads();
  float* ex = reinterpret_cast<float*>(lds);      // 8192 floats = 32KB of the 48KB
  if (grp == 1) {
    #pragma unroll
    for (int m = 0; m < 4; ++m)
      #pragma unroll
      for (int n = 0; n < 4; ++n)
        *reinterpret_cast<f32x4*>(&ex[(w * 16 + m * 4 + n) * 256 + lane * 4]) = acc[m][n];
  }
  __syncthreads();
  if (grp == 0) {
    #pragma unroll
    for (int m = 0; m < 4; ++m) {
      const int rowg = mBase + m * 16 + hi * 4;
      #pragma unroll
      for (int n = 0; n < 4; ++n) {
        const f32x4 p = *reinterpret_cast<const f32x4*>(&ex[(w * 16 + m * 4 + n) * 256 + lane * 4]);
        const int colg = nBase + w * 64 + n * 16 + r16;
        const float bv = bias[colg];
        #pragma unroll
        for (int j = 0; j < 4; ++j)
          C[(size_t)(rowg + j) * OUT_F + colg] = acc[m][n][j] + p[j] + bv;
      }
    }
  }
}

// ---------------- fallback (only if ws too small): direct recompute ----------------
__global__ void naive_out(const float* __restrict__ x, const float* __restrict__ w0,
                          const float* __restrict__ la, const float* __restrict__ lb,
                          const float* __restrict__ qs, const float* __restrict__ bias,
                          float* __restrict__ out) {
  const int n = blockIdx.x * 256 + threadIdx.x;
  const int m = blockIdx.y;
  const float* xr = &x[(size_t)m * IN_F];
  float acc = 0.f;
  for (int kg = 0; kg < IN_F / GROUP; ++kg) {
    const float s = qs[n * (IN_F / GROUP) + kg];
    const float se = s + 1e-9f;
    for (int k0 = 0; k0 < GROUP; ++k0) {
      const int k = kg * GROUP + k0;
      float w = w0[(size_t)n * IN_F + k];
      for (int r = 0; r < RANK; ++r) w = fmaf(lb[n * RANK + r], la[r * IN_F + k], w);
      const float q = rintf(fminf(fmaxf(w / se, -8.f), 7.f));
      acc = fmaf(xr[k], q * s, acc);
    }
  }
  out[(size_t)m * OUT_F + n] = acc + bias[n];
}

extern "C" void kernel_launch(void* const* d_in, const int* in_sizes, int n_in,
                              void* d_out, int out_size, void* d_ws, size_t ws_size,
                              hipStream_t stream) {
  const float* x    = (const float*)d_in[0];
  const float* w0   = (const float*)d_in[1];
  const float* la   = (const float*)d_in[2];
  const float* lb   = (const float*)d_in[3];
  const float* qs   = (const float*)d_in[4];
  const float* bias = (const float*)d_in[5];
  float* out = (float*)d_out;

  const size_t wq_bytes = (size_t)OUT_F * IN_F * 2;
  const size_t xb_bytes = (size_t)MTOK * IN_F * 2;

  if (ws_size >= wq_bytes + xb_bytes) {
    unsigned short* wq = (unsigned short*)d_ws;
    unsigned short* xb = (unsigned short*)((char*)d_ws + wq_bytes);
    quant_w<<<(OUT_F / QROWS) * 4, 256, 0, stream>>>(w0, la, lb, qs, wq);
    cvt_x<<<(MTOK * IN_F) / 1024, 256, 0, stream>>>(x, xb);
    dim3 grid(OUT_F / BN, MTOK / BM);    // 32 x 16 = 512 blocks -> 2 blocks/CU
    gemm_bt<<<grid, 256, 0, stream>>>(xb, wq, bias, out);
  } else {
    dim3 grid(OUT_F / 256, MTOK);
    naive_out<<<grid, 256, 0, stream>>>(x, w0, la, lb, qs, bias, out);
  }
}